// Round 12
// baseline (74.555 us; speedup 1.0000x reference)
//
#include <hip/hip_runtime.h>
#include <hip/hip_fp16.h>

// out[m][n] = fp16( fp16( (sum_k x[m][k]*w6[n][k]) * scale[n] ) + bias[n] ), stored fp32
// v12: BARRIER-FREE streaming GEMM. No LDS at all: MFMA fragments are fed directly
// from global (A from a pre-converted fp16 copy of X in ws; B from fp32 W with
// in-register cvt). Every wave is independent -> compiler software-pipelines the
// load/MFMA stream (barriers were what defeated pipelining in rounds 3-11).
// Split-K with streamed fp32 partials + finalize. Wave tile 64x32.

typedef __attribute__((ext_vector_type(8))) _Float16 half8;
typedef __attribute__((ext_vector_type(2))) __fp16 fp16x2;   // cvt_pkrtz return type
typedef __attribute__((ext_vector_type(4))) float f32x4;

constexpr int K = 4096;
constexpr int N = 4096;
constexpr int M = 256;

__device__ __forceinline__ half8 cvt8(float4 f0, float4 f1) {   // exact: fp16-exact data
    fp16x2 p0 = __builtin_amdgcn_cvt_pkrtz(f0.x, f0.y);
    fp16x2 p1 = __builtin_amdgcn_cvt_pkrtz(f0.z, f0.w);
    fp16x2 p2 = __builtin_amdgcn_cvt_pkrtz(f1.x, f1.y);
    fp16x2 p3 = __builtin_amdgcn_cvt_pkrtz(f1.z, f1.w);
    half8 h;
    h[0]=(_Float16)p0[0]; h[1]=(_Float16)p0[1];
    h[2]=(_Float16)p1[0]; h[3]=(_Float16)p1[1];
    h[4]=(_Float16)p2[0]; h[5]=(_Float16)p2[1];
    h[6]=(_Float16)p3[0]; h[7]=(_Float16)p3[1];
    return h;
}

// X fp32 -> fp16 copy (exact), 8 elems/thread
__global__ __launch_bounds__(256)
void xcvt(const float* __restrict__ X, _Float16* __restrict__ X16)
{
    const int i = ((int)blockIdx.x * 256 + (int)threadIdx.x) * 8;
    float4 a = *(const float4*)(X + i);
    float4 b = *(const float4*)(X + i + 4);
    *(half8*)(X16 + i) = cvt8(a, b);
}

// one wave per block; wave tile 64(m) x 32(n); K-slice KSPL; no LDS, no barriers.
template <int SPL>
__global__ __launch_bounds__(64, 1)
void gemm_stream(const _Float16* __restrict__ X16,
                 const float* __restrict__ W,
                 float* __restrict__ P)          // [SPL][M][N] fp32 partials
{
    constexpr int KSPL = K / SPL;

    const int l  = (int)threadIdx.x;   // 0..63
    const int lc = l & 15;             // frag row/col
    const int lr = l >> 4;             // frag k-group

    // XCD swizzle: grid = 4(mb) x 128(nb) x SPL, 8 XCDs round-robin on bid&7.
    // Per XCD: nb range [16*xcd, 16*xcd+16) -> W rows 512 x K read once from HBM,
    // X16 (2 MB) fully L2-resident. W-sharers (mb=0..3, same nb/sp) adjacent in i.
    const int bid = (int)blockIdx.x;
    const int xcd = bid & 7;
    const int i   = bid >> 3;          // 0 .. 64*SPL-1
    const int sp  = i % SPL;
    const int j   = i / SPL;           // 0..63
    const int mb  = j & 3;
    const int nbl = j >> 2;            // 0..15
    const int bm  = mb * 64;
    const int bn  = (xcd * 16 + nbl) * 32;
    const int kb  = sp * KSPL;

    // A: lane reads X16[bm + 16*ar + lc][kb + k0 + 8*lr .. +8]   (16 B, one load)
    // B: lane reads W  [bn + 16*br + lc][kb + k0 + 8*lr .. +8]   (32 B, two loads + cvt)
    const _Float16* xb = X16 + (size_t)(bm + lc) * K + kb + lr * 8;
    const float*    wb = W   + (size_t)(bn + lc) * K + kb + lr * 8;

    f32x4 acc[4][2];
    #pragma unroll
    for (int a = 0; a < 4; ++a)
        #pragma unroll
        for (int b = 0; b < 2; ++b)
            acc[a][b] = (f32x4){0.f, 0.f, 0.f, 0.f};

    #pragma unroll 4
    for (int k0 = 0; k0 < KSPL; k0 += 32) {
        half8 a0 = *(const half8*)(xb + 0 * 16 * K + k0);
        half8 a1 = *(const half8*)(xb + 1 * 16 * K + k0);
        half8 a2 = *(const half8*)(xb + 2 * 16 * K + k0);
        half8 a3 = *(const half8*)(xb + 3 * 16 * K + k0);
        float4 w00 = *(const float4*)(wb + 0 * 16 * K + k0);
        float4 w01 = *(const float4*)(wb + 0 * 16 * K + k0 + 4);
        float4 w10 = *(const float4*)(wb + 1 * 16 * K + k0);
        float4 w11 = *(const float4*)(wb + 1 * 16 * K + k0 + 4);
        half8 b0 = cvt8(w00, w01);
        half8 b1 = cvt8(w10, w11);
        acc[0][0] = __builtin_amdgcn_mfma_f32_16x16x32_f16(a0, b0, acc[0][0], 0, 0, 0);
        acc[1][0] = __builtin_amdgcn_mfma_f32_16x16x32_f16(a1, b0, acc[1][0], 0, 0, 0);
        acc[2][0] = __builtin_amdgcn_mfma_f32_16x16x32_f16(a2, b0, acc[2][0], 0, 0, 0);
        acc[3][0] = __builtin_amdgcn_mfma_f32_16x16x32_f16(a3, b0, acc[3][0], 0, 0, 0);
        acc[0][1] = __builtin_amdgcn_mfma_f32_16x16x32_f16(a0, b1, acc[0][1], 0, 0, 0);
        acc[1][1] = __builtin_amdgcn_mfma_f32_16x16x32_f16(a1, b1, acc[1][1], 0, 0, 0);
        acc[2][1] = __builtin_amdgcn_mfma_f32_16x16x32_f16(a2, b1, acc[2][1], 0, 0, 0);
        acc[3][1] = __builtin_amdgcn_mfma_f32_16x16x32_f16(a3, b1, acc[3][1], 0, 0, 0);
    }

    // C/D layout: col = lane&15, row = 4*(lane>>4)+reg  [m89/m91]
    float* Pb = P + (size_t)sp * M * N;
    #pragma unroll
    for (int ar = 0; ar < 4; ++ar)
        #pragma unroll
        for (int br = 0; br < 2; ++br)
            #pragma unroll
            for (int r = 0; r < 4; ++r)
                Pb[(size_t)(bm + ar * 16 + lr * 4 + r) * N + bn + br * 16 + lc]
                    = acc[ar][br][r];
}

// O = fp32( fp16( fp16( (sum of SPL partials) * scale[n] ) + bias[n] ) )
template <int SPL>
__global__ __launch_bounds__(256)
void finalize(const float* __restrict__ P,
              const float* __restrict__ S,
              const float* __restrict__ Bi,
              float* __restrict__ O)
{
    const size_t i = ((size_t)blockIdx.x * 256 + threadIdx.x) * 4;
    const int n = (int)(i & (N - 1));
    float4 v = *(const float4*)(P + i);
    #pragma unroll
    for (int s = 1; s < SPL; ++s) {
        float4 u = *(const float4*)(P + (size_t)s * M * N + i);
        v.x += u.x; v.y += u.y; v.z += u.z; v.w += u.w;
    }
    float4 sc = *(const float4*)(S + n);
    float4 bb = *(const float4*)(Bi + n);
    v.x = (float)(_Float16)((float)(_Float16)(v.x * sc.x) + bb.x);
    v.y = (float)(_Float16)((float)(_Float16)(v.y * sc.y) + bb.y);
    v.z = (float)(_Float16)((float)(_Float16)(v.z * sc.z) + bb.z);
    v.w = (float)(_Float16)((float)(_Float16)(v.w * sc.w) + bb.w);
    *(float4*)(O + i) = v;
}

// correctness fallback if d_ws is too small
__global__ __launch_bounds__(256)
void fp6lin_small(const float* __restrict__ X, const float* __restrict__ W,
                  const float* __restrict__ S, const float* __restrict__ Bi,
                  float* __restrict__ O)
{
    const int n = (int)blockIdx.x;
    const int m = (int)threadIdx.x;
    float s = 0.f;
    for (int k = 0; k < K; ++k)
        s += (float)(_Float16)X[(size_t)m * K + k] * (float)(_Float16)W[(size_t)n * K + k];
    O[(size_t)m * N + n] = (float)(_Float16)((float)(_Float16)(s * S[n]) + Bi[n]);
}

extern "C" void kernel_launch(void* const* d_in, const int* in_sizes, int n_in,
                              void* d_out, int out_size, void* d_ws, size_t ws_size,
                              hipStream_t stream) {
    const float* x  = (const float*)d_in[0];
    const float* w  = (const float*)d_in[1];
    const float* s  = (const float*)d_in[2];
    const float* bi = (const float*)d_in[3];
    float* o = (float*)d_out;

    const size_t xbytes = (size_t)M * K * 2;              // 2 MB fp16 X
    const size_t slice  = (size_t)M * N * sizeof(float);  // 4 MB per partial
    _Float16* x16 = (_Float16*)d_ws;
    float*    P   = (float*)((char*)d_ws + xbytes);

    const int fin_grid = M * N / 4 / 256;                 // 1024

    if (ws_size >= xbytes + 4 * slice) {
        xcvt<<<dim3(M * K / 8 / 256), dim3(256), 0, stream>>>(x, x16);
        gemm_stream<4><<<dim3(4 * 128 * 4), dim3(64), 0, stream>>>(x16, w, P);
        finalize<4><<<dim3(fin_grid), dim3(256), 0, stream>>>(P, s, bi, o);
    } else if (ws_size >= xbytes + 2 * slice) {
        xcvt<<<dim3(M * K / 8 / 256), dim3(256), 0, stream>>>(x, x16);
        gemm_stream<2><<<dim3(4 * 128 * 2), dim3(64), 0, stream>>>(x16, w, P);
        finalize<2><<<dim3(fin_grid), dim3(256), 0, stream>>>(P, s, bi, o);
    } else {
        fp6lin_small<<<dim3(N), dim3(M), 0, stream>>>(x, w, s, bi, o);
    }
}

// Round 13
// 63.459 us; speedup vs baseline: 1.1749x; 1.1749x over previous
//
#include <hip/hip_runtime.h>
#include <hip/hip_fp16.h>

// out[m][n] = fp16( fp16( (sum_k x[m][k]*w6[n][k]) * scale[n] ) + bias[n] ), stored fp32
// v13: MAX-OCCUPANCY gemm. Evidence (r7: 2.7 TB/s @62% occ vs r8/r12: 1.3/0.9 TB/s
// @<=30%): achieved memory BW scales with resident load-issuing waves. 64x64 tile,
// 256 thr, SPL=8 -> 2048 blocks = 8 blocks/CU = 32 waves/CU. Single-buf fp16 LDS,
// X pre-converted fp16 (L2-resident), streamed fp32 partials, finalize sums 8.

typedef __attribute__((ext_vector_type(8))) _Float16 half8;
typedef __attribute__((ext_vector_type(2))) __fp16 fp16x2;   // cvt_pkrtz return type
typedef __attribute__((ext_vector_type(4))) float f32x4;

constexpr int K = 4096, N = 4096, M = 256;
constexpr int BM = 64, BN = 64, BK = 64;
constexpr int LDH = BK + 8;         // 72 halves = 144 B row stride
constexpr int TH  = BM * LDH;       // 4608 halves per op tile (9216 B)

__device__ __forceinline__ half8 cvt8(float4 f0, float4 f1) {   // exact: fp16-exact data
    fp16x2 p0 = __builtin_amdgcn_cvt_pkrtz(f0.x, f0.y);
    fp16x2 p1 = __builtin_amdgcn_cvt_pkrtz(f0.z, f0.w);
    fp16x2 p2 = __builtin_amdgcn_cvt_pkrtz(f1.x, f1.y);
    fp16x2 p3 = __builtin_amdgcn_cvt_pkrtz(f1.z, f1.w);
    half8 h;
    h[0]=(_Float16)p0[0]; h[1]=(_Float16)p0[1];
    h[2]=(_Float16)p1[0]; h[3]=(_Float16)p1[1];
    h[4]=(_Float16)p2[0]; h[5]=(_Float16)p2[1];
    h[6]=(_Float16)p3[0]; h[7]=(_Float16)p3[1];
    return h;
}

// X fp32 -> fp16 copy (exact), 8 elems/thread
__global__ __launch_bounds__(256)
void xcvt(const float* __restrict__ X, _Float16* __restrict__ X16)
{
    const int i = ((int)blockIdx.x * 256 + (int)threadIdx.x) * 8;
    float4 a = *(const float4*)(X + i);
    float4 b = *(const float4*)(X + i + 4);
    *(half8*)(X16 + i) = cvt8(a, b);
}

template <int SPL>
__global__ __launch_bounds__(256, 8)    // 8 blocks/CU; r8 measured 52 VGPR on this shape
void gemm(const _Float16* __restrict__ X16,
          const float* __restrict__ W,
          float* __restrict__ P)        // [SPL][M][N] fp32 partials
{
    constexpr int KSPL = K / SPL;
    constexpr int NPH  = KSPL / BK;

    __shared__ __align__(16) _Float16 LA[TH];
    __shared__ __align__(16) _Float16 LB[TH];

    const int tid = (int)threadIdx.x;
    const int l   = tid & 63;
    const int wv  = tid >> 6;           // 4 waves: 2(M) x 2(N), wave tile 32x32
    const int lc  = l & 15;
    const int lr  = l >> 4;
    const int wm  = (wv & 1) * 32;
    const int wn  = (wv >> 1) * 32;

    // XCD swizzle: per XCD an N-range of 8 tiles (512 rows: W 8MB HBM-read once/XCD);
    // mb fastest -> 4 blocks sharing a W k-panel are co-resident on the XCD.
    const int bid = (int)blockIdx.x;
    const int xcd = bid & 7;
    const int i   = bid >> 3;
    const int mb  = i & 3;
    const int j   = i >> 2;
    const int sp  = j % SPL;
    const int nb  = xcd * 8 + j / SPL;
    const int bm  = mb * BM, bn = nb * BN, kb = sp * KSPL;

    // staging: thread t -> row t>>2 (0..63), 16 elems at col (t&3)*16
    const int srow = tid >> 2;
    const int scol = (tid & 3) * 16;
    const _Float16* xs = X16 + (size_t)(bm + srow) * K + kb + scol;
    const float*    wg = W   + (size_t)(bn + srow) * K + kb + scol;
    _Float16* la = LA + srow * LDH + scol;
    _Float16* lb = LB + srow * LDH + scol;

    // frag read pointers (16x16x32: row = lane&15, k = (lane>>4)*8 + j)
    const _Float16* pa = LA + (wm + lc) * LDH + lr * 8;
    const _Float16* pb = LB + (wn + lc) * LDH + lr * 8;

    f32x4 acc[2][2];
    #pragma unroll
    for (int a = 0; a < 2; ++a)
        #pragma unroll
        for (int b = 0; b < 2; ++b)
            acc[a][b] = (f32x4){0.f, 0.f, 0.f, 0.f};

    for (int t = 0; t < NPH; ++t) {
        if (t) __syncthreads();
        // A: fp16 memcpy (32 B/thread); W: fp32 load + exact cvt (64 B/thread)
        half8  a0 = *(const half8*)(xs + t * BK);
        half8  a1 = *(const half8*)(xs + t * BK + 8);
        float4 w0 = *(const float4*)(wg + t * BK);
        float4 w1 = *(const float4*)(wg + t * BK + 4);
        float4 w2 = *(const float4*)(wg + t * BK + 8);
        float4 w3 = *(const float4*)(wg + t * BK + 12);
        *(half8*)(la)     = a0;
        *(half8*)(la + 8) = a1;
        *(half8*)(lb)     = cvt8(w0, w1);
        *(half8*)(lb + 8) = cvt8(w2, w3);
        __syncthreads();

        #pragma unroll
        for (int kk = 0; kk < 2; ++kk) {
            half8 af0 = *(const half8*)(pa + kk * 32);
            half8 af1 = *(const half8*)(pa + 16 * LDH + kk * 32);
            half8 bf0 = *(const half8*)(pb + kk * 32);
            half8 bf1 = *(const half8*)(pb + 16 * LDH + kk * 32);
            acc[0][0] = __builtin_amdgcn_mfma_f32_16x16x32_f16(af0, bf0, acc[0][0], 0, 0, 0);
            acc[1][0] = __builtin_amdgcn_mfma_f32_16x16x32_f16(af1, bf0, acc[1][0], 0, 0, 0);
            acc[0][1] = __builtin_amdgcn_mfma_f32_16x16x32_f16(af0, bf1, acc[0][1], 0, 0, 0);
            acc[1][1] = __builtin_amdgcn_mfma_f32_16x16x32_f16(af1, bf1, acc[1][1], 0, 0, 0);
        }
    }

    // streamed partial stores. C/D: col = lane&15, row = (lane>>4)*4 + reg [m89/m91]
    float* Pb = P + (size_t)sp * M * N;
    const int orow = bm + wm + lr * 4;
    const int ocol = bn + wn + lc;
    #pragma unroll
    for (int ar = 0; ar < 2; ++ar)
        #pragma unroll
        for (int br = 0; br < 2; ++br)
            #pragma unroll
            for (int r = 0; r < 4; ++r)
                Pb[(size_t)(orow + ar * 16 + r) * N + ocol + br * 16] = acc[ar][br][r];
}

// O = fp32( fp16( fp16( (sum of SPL partials) * scale[n] ) + bias[n] ) )
template <int SPL>
__global__ __launch_bounds__(256)
void finalize(const float* __restrict__ P,
              const float* __restrict__ S,
              const float* __restrict__ Bi,
              float* __restrict__ O)
{
    const size_t i = ((size_t)blockIdx.x * 256 + threadIdx.x) * 4;
    const int n = (int)(i & (N - 1));
    float4 v = *(const float4*)(P + i);
    #pragma unroll
    for (int s = 1; s < SPL; ++s) {
        float4 u = *(const float4*)(P + (size_t)s * M * N + i);
        v.x += u.x; v.y += u.y; v.z += u.z; v.w += u.w;
    }
    float4 sc = *(const float4*)(S + n);
    float4 bb = *(const float4*)(Bi + n);
    v.x = (float)(_Float16)((float)(_Float16)(v.x * sc.x) + bb.x);
    v.y = (float)(_Float16)((float)(_Float16)(v.y * sc.y) + bb.y);
    v.z = (float)(_Float16)((float)(_Float16)(v.z * sc.z) + bb.z);
    v.w = (float)(_Float16)((float)(_Float16)(v.w * sc.w) + bb.w);
    *(float4*)(O + i) = v;
}

// correctness fallback if d_ws is too small
__global__ __launch_bounds__(256)
void fp6lin_small(const float* __restrict__ X, const float* __restrict__ W,
                  const float* __restrict__ S, const float* __restrict__ Bi,
                  float* __restrict__ O)
{
    const int n = (int)blockIdx.x;
    const int m = (int)threadIdx.x;
    float s = 0.f;
    for (int k = 0; k < K; ++k)
        s += (float)(_Float16)X[(size_t)m * K + k] * (float)(_Float16)W[(size_t)n * K + k];
    O[(size_t)m * N + n] = (float)(_Float16)((float)(_Float16)(s * S[n]) + Bi[n]);
}

extern "C" void kernel_launch(void* const* d_in, const int* in_sizes, int n_in,
                              void* d_out, int out_size, void* d_ws, size_t ws_size,
                              hipStream_t stream) {
    const float* x  = (const float*)d_in[0];
    const float* w  = (const float*)d_in[1];
    const float* s  = (const float*)d_in[2];
    const float* bi = (const float*)d_in[3];
    float* o = (float*)d_out;

    const size_t xbytes = (size_t)M * K * 2;              // 2 MB fp16 X
    const size_t slice  = (size_t)M * N * sizeof(float);  // 4 MB per partial
    _Float16* x16 = (_Float16*)d_ws;
    float*    P   = (float*)((char*)d_ws + xbytes);
    const int fin_grid = M * N / 4 / 256;                 // 1024

    if (ws_size >= xbytes + 8 * slice) {
        xcvt<<<dim3(M * K / 8 / 256), dim3(256), 0, stream>>>(x, x16);
        gemm<8><<<dim3(4 * 64 * 8), dim3(256), 0, stream>>>(x16, w, P);
        finalize<8><<<dim3(fin_grid), dim3(256), 0, stream>>>(P, s, bi, o);
    } else if (ws_size >= xbytes + 4 * slice) {
        xcvt<<<dim3(M * K / 8 / 256), dim3(256), 0, stream>>>(x, x16);
        gemm<4><<<dim3(4 * 64 * 4), dim3(256), 0, stream>>>(x16, w, P);
        finalize<4><<<dim3(fin_grid), dim3(256), 0, stream>>>(P, s, bi, o);
    } else {
        fp6lin_small<<<dim3(N), dim3(M), 0, stream>>>(x, w, s, bi, o);
    }
}

// Round 14
// 41.493 us; speedup vs baseline: 1.7968x; 1.5294x over previous
//
#include <hip/hip_runtime.h>
#include <hip/hip_fp16.h>

// out[m][n] = fp16( fp16( (sum_k x[m][k]*w6[n][k]) * scale[n] ) + bias[n] ), stored fp32
// v14: counted-vmcnt DMA pipeline (T3+T4). global_load_lds staging (6 DMA/wave/phase),
// 2-tile-deep prefetch, loop waits vmcnt(6) + RAW s_barrier (never drains the stream;
// __syncthreads' vmcnt(0) drain was the cross-round killer). 64x64 tile, BK=64, SPL=4,
// ~3 blocks/CU. XOR chunk swizzle both sides (r11-proven). X pre-converted to fp16.

typedef __attribute__((ext_vector_type(8))) _Float16 half8;
typedef __attribute__((ext_vector_type(2))) __fp16 fp16x2;   // cvt_pkrtz return type
typedef __attribute__((ext_vector_type(4))) float f32x4;

typedef const __attribute__((address_space(1))) void* gptr_t;
typedef __attribute__((address_space(3))) void* lptr_t;

constexpr int K = 4096, N = 4096, M = 256;
constexpr int BM = 64, BN = 64, BK = 64;
constexpr int SPL = 4;
constexpr int KSPL = K / SPL;     // 1024
constexpr int NT = KSPL / BK;     // 16 phases

__device__ __forceinline__ void gload16(const void* g, void* l) {
    __builtin_amdgcn_global_load_lds((gptr_t)g, (lptr_t)l, 16, 0, 0);
}

__device__ __forceinline__ half8 cvt8(float4 f0, float4 f1) {   // exact: fp16-exact data
    fp16x2 p0 = __builtin_amdgcn_cvt_pkrtz(f0.x, f0.y);
    fp16x2 p1 = __builtin_amdgcn_cvt_pkrtz(f0.z, f0.w);
    fp16x2 p2 = __builtin_amdgcn_cvt_pkrtz(f1.x, f1.y);
    fp16x2 p3 = __builtin_amdgcn_cvt_pkrtz(f1.z, f1.w);
    half8 h;
    h[0]=(_Float16)p0[0]; h[1]=(_Float16)p0[1];
    h[2]=(_Float16)p1[0]; h[3]=(_Float16)p1[1];
    h[4]=(_Float16)p2[0]; h[5]=(_Float16)p2[1];
    h[6]=(_Float16)p3[0]; h[7]=(_Float16)p3[1];
    return h;
}

// X fp32 -> fp16 copy (exact), 8 elems/thread
__global__ __launch_bounds__(256)
void xcvt(const float* __restrict__ X, _Float16* __restrict__ X16)
{
    const int i = ((int)blockIdx.x * 256 + (int)threadIdx.x) * 8;
    float4 a = *(const float4*)(X + i);
    float4 b = *(const float4*)(X + i + 4);
    *(half8*)(X16 + i) = cvt8(a, b);
}

__global__ __launch_bounds__(256, 3)
void gemm(const _Float16* __restrict__ X16,
          const float* __restrict__ W,
          float* __restrict__ P)        // [SPL][M][N] fp32 partials
{
    // A tiles: fp16 [2][64][64]  (16 KB) ; W tiles: fp32 [2][64][64] (32 KB)
    __shared__ __align__(16) _Float16 LA[2][BM * BK];
    __shared__ __align__(16) float    LB[2][BN * BK];

    const int tid = (int)threadIdx.x;
    const int l   = tid & 63;
    const int wv  = tid >> 6;           // 4 waves: 2(M) x 2(N), wave tile 32x32
    const int lc  = l & 15;
    const int lr  = l >> 4;
    const int wm  = (wv & 1) * 32;
    const int wn  = (wv >> 1) * 32;

    // XCD swizzle: per XCD 8 N-tiles (512 W rows, HBM-read once); mb fastest so the
    // 4 blocks sharing a W k-slab are co-resident on one XCD.
    const int bid = (int)blockIdx.x;
    const int xcd = bid & 7;
    const int i   = bid >> 3;           // 0..127
    const int mb  = i & 3;
    const int j   = i >> 2;             // 0..31
    const int sp  = j & 3;
    const int nbl = j >> 2;             // 0..7
    const int bm  = mb * BM;
    const int bn  = (xcd * 8 + nbl) * BN;
    const int kb  = sp * KSPL;

    // ---- DMA staging maps (LDS linear, global source pre-XOR-swizzled) ----
    // A: 2 insts/wave, each 1KB = 8 rows x 128B. lane: row=l>>3, 16B chunk=(l&7)^(l>>3).
    const int arow0 = wv * 16 + (l >> 3);            // + 8 per inst s
    const int acho  = ((l & 7) ^ (l >> 3)) * 8;      // halves
    const _Float16* ag0 = X16 + (size_t)(bm + arow0)     * K + kb + acho;
    const _Float16* ag1 = X16 + (size_t)(bm + arow0 + 8) * K + kb + acho;
    const int asl0 = (wv * 16) * BK;                 // LDS half-index, + 8*BK per inst
    const int asl1 = (wv * 16 + 8) * BK;
    // W: 4 insts/wave, each 1KB = 4 rows x 256B. lane: row=l>>4, 16B chunk:
    // d = ((l&15)^(l>>4)) ^ ((s&1)*4)   (row&7 = (s&1)*4 + (l>>4))
    const int wrow0 = wv * 16 + (l >> 4);            // + 4 per inst s
    const int wce   = ((l & 15) ^ (l >> 4)) * 4;     // floats, even s
    const int wco   = (((l & 15) ^ (l >> 4)) ^ 4) * 4; // odd s
    const float* wg0 = W + (size_t)(bn + wrow0)      * K + kb + wce;
    const float* wg1 = W + (size_t)(bn + wrow0 + 4)  * K + kb + wco;
    const float* wg2 = W + (size_t)(bn + wrow0 + 8)  * K + kb + wce;
    const float* wg3 = W + (size_t)(bn + wrow0 + 12) * K + kb + wco;
    const int wsl0 = (wv * 16 + 0)  * BK;            // LDS float-index per inst
    const int wsl1 = (wv * 16 + 4)  * BK;
    const int wsl2 = (wv * 16 + 8)  * BK;
    const int wsl3 = (wv * 16 + 12) * BK;

#define STAGE(t, bf) do {                                               \
        gload16(ag0 + (size_t)(t) * BK, &LA[bf][asl0]);                 \
        gload16(ag1 + (size_t)(t) * BK, &LA[bf][asl1]);                 \
        gload16(wg0 + (size_t)(t) * BK, &LB[bf][wsl0]);                 \
        gload16(wg1 + (size_t)(t) * BK, &LB[bf][wsl1]);                 \
        gload16(wg2 + (size_t)(t) * BK, &LB[bf][wsl2]);                 \
        gload16(wg3 + (size_t)(t) * BK, &LB[bf][wsl3]);                 \
    } while (0)   // exactly 6 vmem ops per wave per tile

    // ---- frag read offsets (swizzled) ----
    // A: row ra = wm+16ar+lc (ra&7 = lc&7); chunk = (kk*4+lr)^(lc&7)
    const int aBase = (wm + lc) * BK;
    const int ka0 = (((0 * 4 + lr) ^ (lc & 7)) << 3);
    const int ka1 = (((1 * 4 + lr) ^ (lc & 7)) << 3);
    // W: row rb = wn+16br+lc; chunk(4 floats) = (kk*8+lr*2+h)^(lc&7)
    const int wBase = (wn + lc) * BK;
    const int kw00 = (((0 * 8 + lr * 2 + 0) ^ (lc & 7)) << 2);
    const int kw01 = (((0 * 8 + lr * 2 + 1) ^ (lc & 7)) << 2);
    const int kw10 = (((1 * 8 + lr * 2 + 0) ^ (lc & 7)) << 2);
    const int kw11 = (((1 * 8 + lr * 2 + 1) ^ (lc & 7)) << 2);

    f32x4 acc[2][2];
    #pragma unroll
    for (int a = 0; a < 2; ++a)
        #pragma unroll
        for (int b = 0; b < 2; ++b)
            acc[a][b] = (f32x4){0.f, 0.f, 0.f, 0.f};

#define COMPUTE(bf) do {                                                \
        _Pragma("unroll")                                               \
        for (int kk = 0; kk < 2; ++kk) {                                \
            const int ka = kk ? ka1 : ka0;                              \
            const int k0 = kk ? kw10 : kw00;                            \
            const int k1 = kk ? kw11 : kw01;                            \
            half8 a0 = *(const half8*)(&LA[bf][aBase + ka]);            \
            half8 a1 = *(const half8*)(&LA[bf][aBase + 16 * BK + ka]);  \
            float4 b00 = *(const float4*)(&LB[bf][wBase + k0]);         \
            float4 b01 = *(const float4*)(&LB[bf][wBase + k1]);         \
            float4 b10 = *(const float4*)(&LB[bf][wBase + 16 * BK + k0]); \
            float4 b11 = *(const float4*)(&LB[bf][wBase + 16 * BK + k1]); \
            half8 f0 = cvt8(b00, b01);                                  \
            half8 f1 = cvt8(b10, b11);                                  \
            acc[0][0] = __builtin_amdgcn_mfma_f32_16x16x32_f16(a0, f0, acc[0][0], 0, 0, 0); \
            acc[1][0] = __builtin_amdgcn_mfma_f32_16x16x32_f16(a1, f0, acc[1][0], 0, 0, 0); \
            acc[0][1] = __builtin_amdgcn_mfma_f32_16x16x32_f16(a0, f1, acc[0][1], 0, 0, 0); \
            acc[1][1] = __builtin_amdgcn_mfma_f32_16x16x32_f16(a1, f1, acc[1][1], 0, 0, 0); \
        } } while (0)

    // prologue: prime 2 tiles (12 outstanding DMA per wave)
    STAGE(0, 0);
    STAGE(1, 1);

    for (int t = 0; t < NT; ++t) {
        // wait ONLY for tile t's 6 loads; tile t+1's 6 stay in flight.
        if (t == NT - 1) { asm volatile("s_waitcnt vmcnt(0)" ::: "memory"); }
        else             { asm volatile("s_waitcnt vmcnt(6)" ::: "memory"); }
        __builtin_amdgcn_sched_barrier(0);
        __builtin_amdgcn_s_barrier();        // raw barrier: NO vmcnt(0) drain
        COMPUTE(t & 1);
        __builtin_amdgcn_sched_barrier(0);
        __builtin_amdgcn_s_barrier();        // all waves done reading buf t&1
        if (t + 2 < NT) STAGE(t + 2, t & 1); // refill freed buffer
    }
#undef STAGE
#undef COMPUTE

    // streamed partial stores. C/D: col = lane&15, row = (lane>>4)*4 + reg [m89/m91]
    float* Pb = P + (size_t)sp * M * N;
    const int orow = bm + wm + lr * 4;
    const int ocol = bn + wn + lc;
    #pragma unroll
    for (int ar = 0; ar < 2; ++ar)
        #pragma unroll
        for (int br = 0; br < 2; ++br)
            #pragma unroll
            for (int r = 0; r < 4; ++r)
                Pb[(size_t)(orow + ar * 16 + r) * N + ocol + br * 16] = acc[ar][br][r];
}

// O = fp32( fp16( fp16( (sum of SPL partials) * scale[n] ) + bias[n] ) )
template <int SPLT>
__global__ __launch_bounds__(256)
void finalize(const float* __restrict__ P,
              const float* __restrict__ S,
              const float* __restrict__ Bi,
              float* __restrict__ O)
{
    const size_t i = ((size_t)blockIdx.x * 256 + threadIdx.x) * 4;
    const int n = (int)(i & (N - 1));
    float4 v = *(const float4*)(P + i);
    #pragma unroll
    for (int s = 1; s < SPLT; ++s) {
        float4 u = *(const float4*)(P + (size_t)s * M * N + i);
        v.x += u.x; v.y += u.y; v.z += u.z; v.w += u.w;
    }
    float4 sc = *(const float4*)(S + n);
    float4 bb = *(const float4*)(Bi + n);
    v.x = (float)(_Float16)((float)(_Float16)(v.x * sc.x) + bb.x);
    v.y = (float)(_Float16)((float)(_Float16)(v.y * sc.y) + bb.y);
    v.z = (float)(_Float16)((float)(_Float16)(v.z * sc.z) + bb.z);
    v.w = (float)(_Float16)((float)(_Float16)(v.w * sc.w) + bb.w);
    *(float4*)(O + i) = v;
}

// correctness fallback if d_ws is too small
__global__ __launch_bounds__(256)
void fp6lin_small(const float* __restrict__ X, const float* __restrict__ W,
                  const float* __restrict__ S, const float* __restrict__ Bi,
                  float* __restrict__ O)
{
    const int n = (int)blockIdx.x;
    const int m = (int)threadIdx.x;
    float s = 0.f;
    for (int k = 0; k < K; ++k)
        s += (float)(_Float16)X[(size_t)m * K + k] * (float)(_Float16)W[(size_t)n * K + k];
    O[(size_t)m * N + n] = (float)(_Float16)((float)(_Float16)(s * S[n]) + Bi[n]);
}

extern "C" void kernel_launch(void* const* d_in, const int* in_sizes, int n_in,
                              void* d_out, int out_size, void* d_ws, size_t ws_size,
                              hipStream_t stream) {
    const float* x  = (const float*)d_in[0];
    const float* w  = (const float*)d_in[1];
    const float* s  = (const float*)d_in[2];
    const float* bi = (const float*)d_in[3];
    float* o = (float*)d_out;

    const size_t xbytes = (size_t)M * K * 2;              // 2 MB fp16 X
    const size_t slice  = (size_t)M * N * sizeof(float);  // 4 MB per partial
    _Float16* x16 = (_Float16*)d_ws;
    float*    P   = (float*)((char*)d_ws + xbytes);
    const int fin_grid = M * N / 4 / 256;                 // 1024

    if (ws_size >= xbytes + SPL * slice) {
        xcvt<<<dim3(M * K / 8 / 256), dim3(256), 0, stream>>>(x, x16);
        gemm<<<dim3(4 * 64 * SPL), dim3(256), 0, stream>>>(x16, w, P);
        finalize<SPL><<<dim3(fin_grid), dim3(256), 0, stream>>>(P, s, bi, o);
    } else {
        fp6lin_small<<<dim3(N), dim3(M), 0, stream>>>(x, w, s, bi, o);
    }
}

// Round 16
// 36.747 us; speedup vs baseline: 2.0289x; 1.1291x over previous
//
#include <hip/hip_runtime.h>
#include <hip/hip_fp16.h>

// out[m][n] = fp16( fp16( (sum_k x[m][k]*w6[n][k]) * scale[n] ) + bias[n] ), stored fp32
// v15: m97 geometry. 128x128 block, 4 waves, wave-tile 64x64 (16 MFMA per 12 ds_read
// vs r14's 8 per 12 -> 3x LDS-pipe density, the r14 binding resource). BK=32,
// A fp16 (8KB) + W fp32 (16KB) double-buffered = 48KB -> 3 blocks/CU. DMA staging,
// counted vmcnt(6), STAGE issued BEFORE compute (T3). XOR swizzles both sides.
// SPL=8 streamed partials + finalize. X pre-converted fp16 (xcvt).

typedef __attribute__((ext_vector_type(8))) _Float16 half8;
typedef __attribute__((ext_vector_type(2))) __fp16 fp16x2;   // cvt_pkrtz return type
typedef __attribute__((ext_vector_type(4))) float f32x4;

typedef const __attribute__((address_space(1))) void* gptr_t;
typedef __attribute__((address_space(3))) void* lptr_t;

constexpr int K = 4096, N = 4096, M = 256;
constexpr int BM = 128, BN = 128, BK = 32;
constexpr int SPL = 8;
constexpr int KSPL = K / SPL;     // 512
constexpr int NT = KSPL / BK;     // 16 phases

__device__ __forceinline__ void gload16(const void* g, void* l) {
    __builtin_amdgcn_global_load_lds((gptr_t)g, (lptr_t)l, 16, 0, 0);
}

__device__ __forceinline__ half8 cvt8(float4 f0, float4 f1) {   // exact: fp16-exact data
    fp16x2 p0 = __builtin_amdgcn_cvt_pkrtz(f0.x, f0.y);
    fp16x2 p1 = __builtin_amdgcn_cvt_pkrtz(f0.z, f0.w);
    fp16x2 p2 = __builtin_amdgcn_cvt_pkrtz(f1.x, f1.y);
    fp16x2 p3 = __builtin_amdgcn_cvt_pkrtz(f1.z, f1.w);
    half8 h;
    h[0]=(_Float16)p0[0]; h[1]=(_Float16)p0[1];
    h[2]=(_Float16)p1[0]; h[3]=(_Float16)p1[1];
    h[4]=(_Float16)p2[0]; h[5]=(_Float16)p2[1];
    h[6]=(_Float16)p3[0]; h[7]=(_Float16)p3[1];
    return h;
}

// X fp32 -> fp16 copy (exact), 8 elems/thread
__global__ __launch_bounds__(256)
void xcvt(const float* __restrict__ X, _Float16* __restrict__ X16)
{
    const int i = ((int)blockIdx.x * 256 + (int)threadIdx.x) * 8;
    float4 a = *(const float4*)(X + i);
    float4 b = *(const float4*)(X + i + 4);
    *(half8*)(X16 + i) = cvt8(a, b);
}

__global__ __launch_bounds__(256, 3)
void gemm(const _Float16* __restrict__ X16,
          const float* __restrict__ W,
          float* __restrict__ P)        // [SPL][M][N] fp32 partials
{
    __shared__ __align__(16) _Float16 LA[2][BM * BK];   // 2 x 8 KB
    __shared__ __align__(16) float    LB[2][BN * BK];   // 2 x 16 KB

    const int tid = (int)threadIdx.x;
    const int l   = tid & 63;
    const int wv  = tid >> 6;           // 4 waves: 2(M) x 2(N), wave tile 64x64
    const int lc  = l & 15;
    const int lr  = l >> 4;
    const int wm  = (wv & 1) * 64;
    const int wn  = (wv >> 1) * 64;

    // XCD map: per XCD 4 N-tiles (512 W rows, HBM-read once); mb fastest so the
    // 2 blocks sharing a W k-slab are co-resident+co-timed on one XCD.
    const int bid = (int)blockIdx.x;
    const int xcd = bid & 7;
    const int i   = bid >> 3;           // 0..63
    const int mb  = i & 1;
    const int sp  = (i >> 1) & 7;
    const int nbl = i >> 4;             // 0..3
    const int bm  = mb * BM;
    const int bn  = (xcd * 4 + nbl) * BN;
    const int kb  = sp * KSPL;

    // ---- DMA staging (LDS linear dest, global source pre-XOR-swizzled) ----
    // A: 8 KB/phase = 8 insts of 1KB (16 rows x 64B); wave wv does insts {2wv, 2wv+1}.
    //    lane l -> row l>>2, chunk l&3 (16B chunks); source chunk = (l&3)^((l>>3)&3).
    const int arow = wv * 32 + (l >> 2);             // +16 for inst 1
    const int acho = ((l & 3) ^ ((l >> 3) & 3)) * 8; // halves
    const _Float16* ag0 = X16 + (size_t)(bm + arow)      * K + kb + acho;
    const _Float16* ag1 = X16 + (size_t)(bm + arow + 16) * K + kb + acho;
    const int asl0 = (wv * 32) * BK;                 // LDS half-index of inst slabs
    const int asl1 = (wv * 32 + 16) * BK;
    // W: 16 KB/phase = 16 insts of 1KB (8 rows x 128B); wave wv does 4 insts.
    //    lane l -> row l>>3, chunk l&7; source chunk = (l&7)^(l>>3).
    const int wrow = wv * 32 + (l >> 3);             // +8 per inst
    const int wcho = ((l & 7) ^ (l >> 3)) * 4;       // floats
    const float* wg0 = W + (size_t)(bn + wrow)      * K + kb + wcho;
    const float* wg1 = W + (size_t)(bn + wrow + 8)  * K + kb + wcho;
    const float* wg2 = W + (size_t)(bn + wrow + 16) * K + kb + wcho;
    const float* wg3 = W + (size_t)(bn + wrow + 24) * K + kb + wcho;
    const int wsl0 = (wv * 32 + 0)  * BK;            // LDS float-index of inst slabs
    const int wsl1 = (wv * 32 + 8)  * BK;
    const int wsl2 = (wv * 32 + 16) * BK;
    const int wsl3 = (wv * 32 + 24) * BK;

#define STAGE(t, bf) do {                                               \
        gload16(ag0 + (size_t)(t) * BK, &LA[bf][asl0]);                 \
        gload16(ag1 + (size_t)(t) * BK, &LA[bf][asl1]);                 \
        gload16(wg0 + (size_t)(t) * BK, &LB[bf][wsl0]);                 \
        gload16(wg1 + (size_t)(t) * BK, &LB[bf][wsl1]);                 \
        gload16(wg2 + (size_t)(t) * BK, &LB[bf][wsl2]);                 \
        gload16(wg3 + (size_t)(t) * BK, &LB[bf][wsl3]);                 \
    } while (0)   // exactly 6 vmem ops per wave per tile

    // ---- frag read offsets (swizzled; verified conflict-free) ----
    // A: row = wm+16ar+lc, chunk lr stored at lr^((row>>1)&3) = lr^((lc>>1)&3)
    const int aswz = (lr ^ ((lc >> 1) & 3)) << 3;    // halves
    // W: row = wn+16br+lc, fp32 chunk-pair {2lr,2lr+1} stored at ^(row&7) = ^(lc&7)
    const int wsz0 = (((lr << 1))     ^ (lc & 7)) << 2;  // floats
    const int wsz1 = (((lr << 1) | 1) ^ (lc & 7)) << 2;

    f32x4 acc[4][4];
    #pragma unroll
    for (int a = 0; a < 4; ++a)
        #pragma unroll
        for (int b = 0; b < 4; ++b)
            acc[a][b] = (f32x4){0.f, 0.f, 0.f, 0.f};

#define COMPUTE(bf) do {                                                \
        half8 af[4];                                                    \
        _Pragma("unroll")                                               \
        for (int ar = 0; ar < 4; ++ar)                                  \
            af[ar] = *(const half8*)(&LA[bf][(wm + ar * 16 + lc) * BK + aswz]); \
        _Pragma("unroll")                                               \
        for (int br = 0; br < 4; ++br) {                                \
            const float* pw = &LB[bf][(wn + br * 16 + lc) * BK];        \
            float4 b0 = *(const float4*)(pw + wsz0);                    \
            float4 b1 = *(const float4*)(pw + wsz1);                    \
            half8 bb = cvt8(b0, b1);                                    \
            acc[0][br] = __builtin_amdgcn_mfma_f32_16x16x32_f16(af[0], bb, acc[0][br], 0, 0, 0); \
            acc[1][br] = __builtin_amdgcn_mfma_f32_16x16x32_f16(af[1], bb, acc[1][br], 0, 0, 0); \
            acc[2][br] = __builtin_amdgcn_mfma_f32_16x16x32_f16(af[2], bb, acc[2][br], 0, 0, 0); \
            acc[3][br] = __builtin_amdgcn_mfma_f32_16x16x32_f16(af[3], bb, acc[3][br], 0, 0, 0); \
        } } while (0)

    // prologue: prime tile 0
    STAGE(0, 0);

    for (int t = 0; t < NT; ++t) {
        if (t + 1 < NT) {
            STAGE(t + 1, (t + 1) & 1);           // issue BEFORE compute (T3)
            asm volatile("s_waitcnt vmcnt(6)" ::: "memory");  // tile t landed
        } else {
            asm volatile("s_waitcnt vmcnt(0)" ::: "memory");
        }
        __builtin_amdgcn_sched_barrier(0);
        __builtin_amdgcn_s_barrier();            // raw barrier: no vmcnt(0) drain
        __builtin_amdgcn_sched_barrier(0);
        COMPUTE(t & 1);
        __builtin_amdgcn_sched_barrier(0);
        __builtin_amdgcn_s_barrier();            // readers done before re-stage
    }
#undef STAGE
#undef COMPUTE

    // streamed partial stores. C/D: col = lane&15, row = (lane>>4)*4 + reg [m89/m91]
    float* Pb = P + (size_t)sp * M * N;
    const int orow = bm + wm + lr * 4;
    const int ocol = bn + wn + lc;
    #pragma unroll
    for (int ar = 0; ar < 4; ++ar)
        #pragma unroll
        for (int br = 0; br < 4; ++br)
            #pragma unroll
            for (int r = 0; r < 4; ++r)
                Pb[(size_t)(orow + ar * 16 + r) * N + ocol + br * 16] = acc[ar][br][r];
}

// O = fp32( fp16( fp16( (sum of SPLT partials) * scale[n] ) + bias[n] ) )
template <int SPLT>
__global__ __launch_bounds__(256)
void finalize(const float* __restrict__ P,
              const float* __restrict__ S,
              const float* __restrict__ Bi,
              float* __restrict__ O)
{
    const size_t i = ((size_t)blockIdx.x * 256 + threadIdx.x) * 4;
    const int n = (int)(i & (N - 1));
    float4 v = *(const float4*)(P + i);
    #pragma unroll
    for (int s = 1; s < SPLT; ++s) {
        float4 u = *(const float4*)(P + (size_t)s * M * N + i);
        v.x += u.x; v.y += u.y; v.z += u.z; v.w += u.w;
    }
    float4 sc = *(const float4*)(S + n);
    float4 bb = *(const float4*)(Bi + n);
    v.x = (float)(_Float16)((float)(_Float16)(v.x * sc.x) + bb.x);
    v.y = (float)(_Float16)((float)(_Float16)(v.y * sc.y) + bb.y);
    v.z = (float)(_Float16)((float)(_Float16)(v.z * sc.z) + bb.z);
    v.w = (float)(_Float16)((float)(_Float16)(v.w * sc.w) + bb.w);
    *(float4*)(O + i) = v;
}

// correctness fallback if d_ws is too small
__global__ __launch_bounds__(256)
void fp6lin_small(const float* __restrict__ X, const float* __restrict__ W,
                  const float* __restrict__ S, const float* __restrict__ Bi,
                  float* __restrict__ O)
{
    const int n = (int)blockIdx.x;
    const int m = (int)threadIdx.x;
    float s = 0.f;
    for (int k = 0; k < K; ++k)
        s += (float)(_Float16)X[(size_t)m * K + k] * (float)(_Float16)W[(size_t)n * K + k];
    O[(size_t)m * N + n] = (float)(_Float16)((float)(_Float16)(s * S[n]) + Bi[n]);
}

extern "C" void kernel_launch(void* const* d_in, const int* in_sizes, int n_in,
                              void* d_out, int out_size, void* d_ws, size_t ws_size,
                              hipStream_t stream) {
    const float* x  = (const float*)d_in[0];
    const float* w  = (const float*)d_in[1];
    const float* s  = (const float*)d_in[2];
    const float* bi = (const float*)d_in[3];
    float* o = (float*)d_out;

    const size_t xbytes = (size_t)M * K * 2;              // 2 MB fp16 X
    const size_t slice  = (size_t)M * N * sizeof(float);  // 4 MB per partial
    _Float16* x16 = (_Float16*)d_ws;
    float*    P   = (float*)((char*)d_ws + xbytes);
    const int fin_grid = M * N / 4 / 256;                 // 1024

    if (ws_size >= xbytes + SPL * slice) {                // 34 MB (r13 confirmed fits)
        xcvt<<<dim3(M * K / 8 / 256), dim3(256), 0, stream>>>(x, x16);
        gemm<<<dim3(2 * 4 * SPL * 8), dim3(256), 0, stream>>>(x16, w, P);
        finalize<SPL><<<dim3(fin_grid), dim3(256), 0, stream>>>(P, s, bi, o);
    } else {
        fp6lin_small<<<dim3(N), dim3(M), 0, stream>>>(x, w, s, bi, o);
    }
}